// Round 10
// baseline (124.503 us; speedup 1.0000x reference)
//
#include <hip/hip_runtime.h>
#include <math.h>

#define GNUM 16
#define CDIM 128
#define SLOT (GNUM*CDIM + 2*GNUM)   // 2080 floats per partial slot
#define NBMAX 2048
#define NRSL 16                      // row-slices for the K2 reduction

typedef float v2f __attribute__((ext_vector_type(2)));

// ---------------- Kernel 1: normalize + register-resident segment accumulate ----------------
// OCCUPANCY-FIRST variant: one row per wave (lane l owns channels 2l,2l+1).
//  - acc[16] v2f = 32 VGPRs (half of R5) + ring-4 float2 slots -> ~55 VGPR total,
//    __launch_bounds__(256,8) => 8 waves/SIMD.
//  - scores[r] is wave-uniform -> scalar load (SGPR ring, zero VGPR).
//  - LDS: ONE 8KB copy, waves merge sequentially (no atomics) -> LDS not occupancy-limiting.
//  - grid 2048 blocks = 8 blocks/CU = 32 waves/CU: 2x the TLP of every previous round.
// Select is branchless cndmask+pk_fma (R4's regression came from scalar BRANCHES, not layout).
__global__ __launch_bounds__(256, 8)
void oc_accum(const float* __restrict__ feat, const int* __restrict__ scores,
              float* __restrict__ partial, int B)
{
    __shared__ float ws_sum[GNUM][CDIM];   // 8 KB
    __shared__ float ws_cnt[GNUM];
    __shared__ float ws_sq [GNUM];

    const int tid  = threadIdx.x;
    const int wave = tid >> 6;
    const int lane = tid & 63;

    v2f acc[GNUM];
    #pragma unroll
    for (int gg = 0; gg < GNUM; ++gg) acc[gg] = (v2f)0.f;
    float cnt = 0.f, sq = 0.f;

    const int gw = __builtin_amdgcn_readfirstlane(blockIdx.x*4 + wave);
    const int nw = gridDim.x*4;

    // contiguous balanced row chunks per wave
    const int base = B / nw;
    const int rem_ = B % nw;
    const int rbeg = gw*base + (gw < rem_ ? gw : rem_);
    const int rcnt = base + (gw < rem_ ? 1 : 0);

    auto process = [&](float2 x, int g) {
        float ss = fmaf(x.x, x.x, x.y*x.y);
        ss += __shfl_xor(ss, 1);
        ss += __shfl_xor(ss, 2);
        ss += __shfl_xor(ss, 4);
        ss += __shfl_xor(ss, 8);
        ss += __shfl_xor(ss, 16);
        ss += __shfl_xor(ss, 32);
        const float inv = (ss > 1e-24f) ? rsqrtf(ss) : 1e12f;   // == 1/max(sqrt(ss),1e-12)
        const v2f xv = {x.x*inv, x.y*inv};
        #pragma unroll
        for (int gg = 0; gg < GNUM; ++gg) {
            const float w = (g == gg) ? 1.0f : 0.0f;   // g is SGPR-uniform
            const v2f wv = {w, w};
            acc[gg] = xv * wv + acc[gg];               // v_pk_fma_f32
        }
        if (lane == g) { cnt += 1.0f; sq = fmaf(ss, inv*inv, sq); }
    };

    const float2* src = reinterpret_cast<const float2*>(feat) + lane;

    if (rcnt > 0) {
        const int rlast = rbeg + rcnt - 1;
        auto LD = [&](int k, float2& x, int& g) {
            int rc = rbeg + k;
            rc = (rc < rlast) ? rc : rlast;            // clamp: branchless, always valid
            x = src[(size_t)rc * 64];
            g = scores[rc];                            // wave-uniform -> s_load
        };

        float2 x0,x1,x2,x3; int g0,g1,g2,g3;
        LD(0,x0,g0); LD(1,x1,g1); LD(2,x2,g2); LD(3,x3,g3);

        int k = 0;
        for (; k + 4 <= rcnt; k += 4) {
            process(x0,g0); LD(k+4, x0,g0);
            process(x1,g1); LD(k+5, x1,g1);
            process(x2,g2); LD(k+6, x2,g2);
            process(x3,g3); LD(k+7, x3,g3);
        }
        const int rem = rcnt - k;          // 0..3
        if (rem > 0) process(x0,g0);
        if (rem > 1) process(x1,g1);
        if (rem > 2) process(x2,g2);
    }

    // sequential (race-free, atomic-free) wave merge into the single LDS copy
    if (wave == 0) {
        #pragma unroll
        for (int gg = 0; gg < GNUM; ++gg)
            *reinterpret_cast<v2f*>(&ws_sum[gg][lane*2]) = acc[gg];
        if (lane < GNUM) { ws_cnt[lane] = cnt; ws_sq[lane] = sq; }
    }
    __syncthreads();
    if (wave == 1) {
        #pragma unroll
        for (int gg = 0; gg < GNUM; ++gg)
            *reinterpret_cast<v2f*>(&ws_sum[gg][lane*2]) += acc[gg];
        if (lane < GNUM) { ws_cnt[lane] += cnt; ws_sq[lane] += sq; }
    }
    __syncthreads();
    if (wave == 2) {
        #pragma unroll
        for (int gg = 0; gg < GNUM; ++gg)
            *reinterpret_cast<v2f*>(&ws_sum[gg][lane*2]) += acc[gg];
        if (lane < GNUM) { ws_cnt[lane] += cnt; ws_sq[lane] += sq; }
    }
    __syncthreads();
    if (wave == 3) {
        #pragma unroll
        for (int gg = 0; gg < GNUM; ++gg)
            *reinterpret_cast<v2f*>(&ws_sum[gg][lane*2]) += acc[gg];
        if (lane < GNUM) { ws_cnt[lane] += cnt; ws_sq[lane] += sq; }
    }
    __syncthreads();

    // write partial slot
    float* out = partial + (size_t)blockIdx.x * SLOT;
    const float* w0 = &ws_sum[0][0];
    for (int e = tid; e < GNUM*CDIM; e += 256)
        out[e] = w0[e];
    if (tid < GNUM) {
        out[GNUM*CDIM + tid]        = ws_cnt[tid];
        out[GNUM*CDIM + GNUM + tid] = ws_sq [tid];
    }
}

// ---------------- Kernel 2: parallel column reduction of partial slots ----------------
// grid (ceil(SLOT/64), NRSL): blockIdx.y picks a row-slice; output NRSL partial vectors.
__global__ __launch_bounds__(256)
void oc_reduce(const float* __restrict__ partial, float* __restrict__ fin8, int nb)
{
    __shared__ float sdata[256];
    const int e     = blockIdx.x*64 + (threadIdx.x & 63);
    const int blane = threadIdx.x >> 6;
    float acc = 0.f;
    if (e < SLOT)
        for (int b = blockIdx.y + blane*NRSL; b < nb; b += 4*NRSL)
            acc += partial[(size_t)b*SLOT + e];
    sdata[threadIdx.x] = acc;
    __syncthreads();
    if (threadIdx.x < 64 && e < SLOT)
        fin8[(size_t)blockIdx.y*SLOT + e] =
            sdata[threadIdx.x] + sdata[threadIdx.x + 64] +
            sdata[threadIdx.x + 128] + sdata[threadIdx.x + 192];
}

// ---------------- Kernel 3: sum slices + remap/compact + loss ----------------
__global__ __launch_bounds__(256)
void oc_loss(const float* __restrict__ fin8, float* __restrict__ out)
{
    __shared__ float FIN[SLOT];
    __shared__ float M[GNUM][CDIM];
    __shared__ float MS[GNUM];
    __shared__ float Cs[GNUM];
    __shared__ int   srcmap[GNUM];
    __shared__ int   Ush;
    __shared__ float red[4];

    const int tid = threadIdx.x;

    for (int e = tid; e < SLOT; e += 256) {
        float a = 0.f;
        #pragma unroll
        for (int r = 0; r < NRSL; ++r) a += fin8[(size_t)r*SLOT + e];
        FIN[e] = a;
    }
    __syncthreads();

    if (tid < GNUM) Cs[tid] = FIN[GNUM*CDIM + tid];
    __syncthreads();

    if (tid == 0) {
        int u = 0;
        for (int g = 0; g < GNUM; ++g)
            if (Cs[g] > 0.f) srcmap[u++] = g;
        Ush = u;
        for (int k = u; k < GNUM; ++k) srcmap[k] = -1;
    }
    __syncthreads();
    const int U = Ush;

    for (int e = tid; e < GNUM*CDIM; e += 256) {
        const int u = e >> 7, c = e & 127;
        const int g = srcmap[u];
        M[u][c] = (g >= 0) ? FIN[g*CDIM + c] / fmaxf(Cs[g], 1.f) : 0.f;
    }
    if (tid < GNUM) {
        const int g = srcmap[tid];
        MS[tid] = (g >= 0) ? FIN[GNUM*CDIM + GNUM + g] / fmaxf(Cs[g], 1.f) : 0.f;
    }
    __syncthreads();

    float acc = 0.f;
    for (int e = tid; e < (GNUM-2)*CDIM; e += 256) {
        const int i = e >> 7, c = e & 127;
        if (i + 2 < U) {
            const float m1 = M[i][c], m2 = M[i+1][c], m3 = M[i+2][c];
            acc += m2*(m1 + m3) - m1*m3;
        }
    }
    acc += __shfl_xor(acc, 1);
    acc += __shfl_xor(acc, 2);
    acc += __shfl_xor(acc, 4);
    acc += __shfl_xor(acc, 8);
    acc += __shfl_xor(acc, 16);
    acc += __shfl_xor(acc, 32);
    if ((tid & 63) == 0) red[tid >> 6] = acc;
    __syncthreads();

    if (tid == 0) {
        float tot = red[0] + red[1] + red[2] + red[3];
        for (int i = 0; i < GNUM-2; ++i)
            if (i + 2 < U) tot -= MS[i+1];
        out[0] = tot / (float)(U - 2);
    }
}

extern "C" void kernel_launch(void* const* d_in, const int* in_sizes, int n_in,
                              void* d_out, int out_size, void* d_ws, size_t ws_size,
                              hipStream_t stream) {
    const float* feat   = (const float*)d_in[0];
    const int*   scores = (const int*)d_in[1];
    float*       out    = (float*)d_out;

    const int B = in_sizes[1];               // number of rows

    // ws layout: [nb * SLOT] partial slots, then [NRSL * SLOT] slice vectors.
    long long cap = (long long)(ws_size / (SLOT * sizeof(float))) - NRSL;
    int nb = (int)(cap < 1 ? 1 : (cap > NBMAX ? NBMAX : cap));

    float* partial = (float*)d_ws;
    float* fin8    = partial + (size_t)nb * SLOT;

    hipLaunchKernelGGL(oc_accum,  dim3(nb), dim3(256), 0, stream, feat, scores, partial, B);
    hipLaunchKernelGGL(oc_reduce, dim3((SLOT + 63) / 64, NRSL), dim3(256), 0, stream, partial, fin8, nb);
    hipLaunchKernelGGL(oc_loss,   dim3(1), dim3(256), 0, stream, fin8, out);
}

// Round 11
// 80.280 us; speedup vs baseline: 1.5509x; 1.5509x over previous
//
#include <hip/hip_runtime.h>
#include <math.h>

#define GNUM 16
#define CDIM 128
#define SLOT (GNUM*CDIM + 2*GNUM)   // 2080 floats per partial slot
#define NBMAX 2048
#define NRSL 16                      // row-slices for the K2 reduction

typedef float v2f __attribute__((ext_vector_type(2)));

// ---------------- Kernel 1: normalize + register-resident segment accumulate ----------------
// One row per wave (lane l owns channels 2l,2l+1 as float2):
//  - acc[16] v2f = 32 VGPRs; ring-6 float2 = 12; total ~70 VGPR.
//  - launch_bounds(256,6): 85-VGPR cap -> NO SPILL (R10's 64-cap spilled acc, 157MB scratch),
//    6 waves/SIMD = 24 waves/CU (1.5x R5's TLP).
//  - scores[r] wave-uniform -> scalar s_load ring (SGPRs, zero VGPR).
//  - select is branchless uniform-weight pk_fma (R4's regression was scalar BRANCHES).
//  - LDS: one 8.7KB copy, sequential wave merge, no atomics (LDS fp atomics = disaster, R7).
__global__ __launch_bounds__(256, 6)
void oc_accum(const float* __restrict__ feat, const int* __restrict__ scores,
              float* __restrict__ partial, int B)
{
    __shared__ float ws_sum[GNUM][CDIM];   // 8 KB
    __shared__ float ws_cnt[GNUM];
    __shared__ float ws_sq [GNUM];

    const int tid  = threadIdx.x;
    const int wave = tid >> 6;
    const int lane = tid & 63;

    v2f acc[GNUM];
    #pragma unroll
    for (int gg = 0; gg < GNUM; ++gg) acc[gg] = (v2f)0.f;
    float cnt = 0.f, sq = 0.f;

    const int gw = __builtin_amdgcn_readfirstlane(blockIdx.x*4 + wave);
    const int nw = gridDim.x*4;

    // contiguous balanced row chunks per wave
    const int base = B / nw;
    const int rem_ = B % nw;
    const int rbeg = gw*base + (gw < rem_ ? gw : rem_);
    const int rcnt = base + (gw < rem_ ? 1 : 0);

    auto process = [&](float2 x, int g) {
        float ss = fmaf(x.x, x.x, x.y*x.y);
        ss += __shfl_xor(ss, 1);
        ss += __shfl_xor(ss, 2);
        ss += __shfl_xor(ss, 4);
        ss += __shfl_xor(ss, 8);
        ss += __shfl_xor(ss, 16);
        ss += __shfl_xor(ss, 32);
        const float inv = (ss > 1e-24f) ? rsqrtf(ss) : 1e12f;   // == 1/max(sqrt(ss),1e-12)
        const v2f xv = {x.x*inv, x.y*inv};
        #pragma unroll
        for (int gg = 0; gg < GNUM; ++gg) {
            const float w = (g == gg) ? 1.0f : 0.0f;   // g is SGPR-uniform -> s_cselect weight
            const v2f wv = {w, w};
            acc[gg] = xv * wv + acc[gg];               // v_pk_fma_f32
        }
        if (lane == g) { cnt += 1.0f; sq = fmaf(ss, inv*inv, sq); }
    };

    const float2* src = reinterpret_cast<const float2*>(feat) + lane;

    if (rcnt > 0) {
        const int rlast = rbeg + rcnt - 1;
        auto LD = [&](int k, float2& x, int& g) {
            int rc = rbeg + k;
            rc = (rc < rlast) ? rc : rlast;            // clamp: branchless, always valid
            x = src[(size_t)rc * 64];
            g = scores[rc];                            // wave-uniform -> s_load
        };

        float2 x0,x1,x2,x3,x4,x5; int g0,g1,g2,g3,g4,g5;
        LD(0,x0,g0); LD(1,x1,g1); LD(2,x2,g2);
        LD(3,x3,g3); LD(4,x4,g4); LD(5,x5,g5);

        int k = 0;
        for (; k + 6 <= rcnt; k += 6) {
            process(x0,g0); LD(k+6,  x0,g0);
            process(x1,g1); LD(k+7,  x1,g1);
            process(x2,g2); LD(k+8,  x2,g2);
            process(x3,g3); LD(k+9,  x3,g3);
            process(x4,g4); LD(k+10, x4,g4);
            process(x5,g5); LD(k+11, x5,g5);
        }
        const int rem = rcnt - k;          // 0..5
        if (rem > 0) process(x0,g0);
        if (rem > 1) process(x1,g1);
        if (rem > 2) process(x2,g2);
        if (rem > 3) process(x3,g3);
        if (rem > 4) process(x4,g4);
    }

    // sequential (race-free, atomic-free) wave merge into the single LDS copy
    if (wave == 0) {
        #pragma unroll
        for (int gg = 0; gg < GNUM; ++gg)
            *reinterpret_cast<v2f*>(&ws_sum[gg][lane*2]) = acc[gg];
        if (lane < GNUM) { ws_cnt[lane] = cnt; ws_sq[lane] = sq; }
    }
    __syncthreads();
    if (wave == 1) {
        #pragma unroll
        for (int gg = 0; gg < GNUM; ++gg)
            *reinterpret_cast<v2f*>(&ws_sum[gg][lane*2]) += acc[gg];
        if (lane < GNUM) { ws_cnt[lane] += cnt; ws_sq[lane] += sq; }
    }
    __syncthreads();
    if (wave == 2) {
        #pragma unroll
        for (int gg = 0; gg < GNUM; ++gg)
            *reinterpret_cast<v2f*>(&ws_sum[gg][lane*2]) += acc[gg];
        if (lane < GNUM) { ws_cnt[lane] += cnt; ws_sq[lane] += sq; }
    }
    __syncthreads();
    if (wave == 3) {
        #pragma unroll
        for (int gg = 0; gg < GNUM; ++gg)
            *reinterpret_cast<v2f*>(&ws_sum[gg][lane*2]) += acc[gg];
        if (lane < GNUM) { ws_cnt[lane] += cnt; ws_sq[lane] += sq; }
    }
    __syncthreads();

    // write partial slot
    float* out = partial + (size_t)blockIdx.x * SLOT;
    const float* w0 = &ws_sum[0][0];
    for (int e = tid; e < GNUM*CDIM; e += 256)
        out[e] = w0[e];
    if (tid < GNUM) {
        out[GNUM*CDIM + tid]        = ws_cnt[tid];
        out[GNUM*CDIM + GNUM + tid] = ws_sq [tid];
    }
}

// ---------------- Kernel 2: parallel column reduction of partial slots ----------------
// grid (ceil(SLOT/64), NRSL): blockIdx.y picks a row-slice; output NRSL partial vectors.
__global__ __launch_bounds__(256)
void oc_reduce(const float* __restrict__ partial, float* __restrict__ fin8, int nb)
{
    __shared__ float sdata[256];
    const int e     = blockIdx.x*64 + (threadIdx.x & 63);
    const int blane = threadIdx.x >> 6;
    float acc = 0.f;
    if (e < SLOT)
        for (int b = blockIdx.y + blane*NRSL; b < nb; b += 4*NRSL)
            acc += partial[(size_t)b*SLOT + e];
    sdata[threadIdx.x] = acc;
    __syncthreads();
    if (threadIdx.x < 64 && e < SLOT)
        fin8[(size_t)blockIdx.y*SLOT + e] =
            sdata[threadIdx.x] + sdata[threadIdx.x + 64] +
            sdata[threadIdx.x + 128] + sdata[threadIdx.x + 192];
}

// ---------------- Kernel 3: sum slices + remap/compact + loss ----------------
__global__ __launch_bounds__(256)
void oc_loss(const float* __restrict__ fin8, float* __restrict__ out)
{
    __shared__ float FIN[SLOT];
    __shared__ float M[GNUM][CDIM];
    __shared__ float MS[GNUM];
    __shared__ float Cs[GNUM];
    __shared__ int   srcmap[GNUM];
    __shared__ int   Ush;
    __shared__ float red[4];

    const int tid = threadIdx.x;

    for (int e = tid; e < SLOT; e += 256) {
        float a = 0.f;
        #pragma unroll
        for (int r = 0; r < NRSL; ++r) a += fin8[(size_t)r*SLOT + e];
        FIN[e] = a;
    }
    __syncthreads();

    if (tid < GNUM) Cs[tid] = FIN[GNUM*CDIM + tid];
    __syncthreads();

    if (tid == 0) {
        int u = 0;
        for (int g = 0; g < GNUM; ++g)
            if (Cs[g] > 0.f) srcmap[u++] = g;
        Ush = u;
        for (int k = u; k < GNUM; ++k) srcmap[k] = -1;
    }
    __syncthreads();
    const int U = Ush;

    for (int e = tid; e < GNUM*CDIM; e += 256) {
        const int u = e >> 7, c = e & 127;
        const int g = srcmap[u];
        M[u][c] = (g >= 0) ? FIN[g*CDIM + c] / fmaxf(Cs[g], 1.f) : 0.f;
    }
    if (tid < GNUM) {
        const int g = srcmap[tid];
        MS[tid] = (g >= 0) ? FIN[GNUM*CDIM + GNUM + g] / fmaxf(Cs[g], 1.f) : 0.f;
    }
    __syncthreads();

    float acc = 0.f;
    for (int e = tid; e < (GNUM-2)*CDIM; e += 256) {
        const int i = e >> 7, c = e & 127;
        if (i + 2 < U) {
            const float m1 = M[i][c], m2 = M[i+1][c], m3 = M[i+2][c];
            acc += m2*(m1 + m3) - m1*m3;
        }
    }
    acc += __shfl_xor(acc, 1);
    acc += __shfl_xor(acc, 2);
    acc += __shfl_xor(acc, 4);
    acc += __shfl_xor(acc, 8);
    acc += __shfl_xor(acc, 16);
    acc += __shfl_xor(acc, 32);
    if ((tid & 63) == 0) red[tid >> 6] = acc;
    __syncthreads();

    if (tid == 0) {
        float tot = red[0] + red[1] + red[2] + red[3];
        for (int i = 0; i < GNUM-2; ++i)
            if (i + 2 < U) tot -= MS[i+1];
        out[0] = tot / (float)(U - 2);
    }
}

extern "C" void kernel_launch(void* const* d_in, const int* in_sizes, int n_in,
                              void* d_out, int out_size, void* d_ws, size_t ws_size,
                              hipStream_t stream) {
    const float* feat   = (const float*)d_in[0];
    const int*   scores = (const int*)d_in[1];
    float*       out    = (float*)d_out;

    const int B = in_sizes[1];               // number of rows

    // ws layout: [nb * SLOT] partial slots, then [NRSL * SLOT] slice vectors.
    long long cap = (long long)(ws_size / (SLOT * sizeof(float))) - NRSL;
    int nb = (int)(cap < 1 ? 1 : (cap > NBMAX ? NBMAX : cap));

    float* partial = (float*)d_ws;
    float* fin8    = partial + (size_t)nb * SLOT;

    hipLaunchKernelGGL(oc_accum,  dim3(nb), dim3(256), 0, stream, feat, scores, partial, B);
    hipLaunchKernelGGL(oc_reduce, dim3((SLOT + 63) / 64, NRSL), dim3(256), 0, stream, partial, fin8, nb);
    hipLaunchKernelGGL(oc_loss,   dim3(1), dim3(256), 0, stream, fin8, out);
}